// Round 9
// baseline (44.181 us; speedup 1.0000x reference)
//
#include <hip/hip_runtime.h>
#include <hip/hip_bf16.h>

#define IN_DIM  8192
#define OUT_DIM 16384
#define BATCH   2048
#define NG      16
#define RROWS   4     // batch rows per block, interleaved f32x4 in LDS
#define TPB     1024
#define NITER   (OUT_DIM / 4 / TPB)   // 4

typedef float        f32x4 __attribute__((ext_vector_type(4)));
typedef unsigned int u32x4 __attribute__((ext_vector_type(4)));

// ---------------------------------------------------------------------------
// Gate mixture is linear in {a*b, a, b, 1}: out = w_ab*ab + w_a*a + w_b*b + w_c.
// ws layout (SoA): [w_ab | w_a | w_b | w_c] (4*OUT_DIM f32), then packed
// indices (OUT_DIM u32: a_idx | b_idx<<16).
// Eval: rows 4i..4i+3 interleaved as f32x4 in LDS -> ONE ds_read_b128 per
// operand index serves 4 rows' outputs. 128 KB dynamic LDS, 1 block/CU,
// 16 waves/CU (empirically sufficient: 32 vs 16 waves/CU was neutral).
// ---------------------------------------------------------------------------

__device__ __forceinline__ void collapse_weights(const float* __restrict__ l,
                                                 float& w_ab, float& w_a,
                                                 float& w_b, float& w_c) {
    float v[NG];
    float m = -1e30f;
#pragma unroll
    for (int k = 0; k < NG; ++k) { v[k] = l[k]; m = fmaxf(m, v[k]); }
    float s = 0.f;
#pragma unroll
    for (int k = 0; k < NG; ++k) { v[k] = __expf(v[k] - m); s += v[k]; }
    float inv = 1.0f / s;
#pragma unroll
    for (int k = 0; k < NG; ++k) v[k] *= inv;
    w_ab = v[1] - v[2] - v[4] - 2.f * v[6] - v[7] + v[8] + 2.f * v[9]
         + v[11] + v[13] - v[14];
    w_a  = v[2] + v[3] + v[6] + v[7] - v[8] - v[9] - v[12] - v[13];
    w_b  = v[4] + v[5] + v[6] + v[7] - v[8] - v[9] - v[10] - v[11];
    w_c  = v[8] + v[9] + v[10] + v[11] + v[12] + v[13] + v[14] + v[15];
}

// Kernel 1: per-column softmax -> SoA coefficients + packed u16 index pairs.
__global__ __launch_bounds__(256) void gate_weights_kernel(
    const float* __restrict__ logits,
    const int* __restrict__ a_idx, const int* __restrict__ b_idx,
    float* __restrict__ ws) {
    int j = blockIdx.x * blockDim.x + threadIdx.x;
    if (j >= OUT_DIM) return;
    float w_ab, w_a, w_b, w_c;
    collapse_weights(logits + (size_t)j * NG, w_ab, w_a, w_b, w_c);
    ws[j]               = w_ab;
    ws[j +     OUT_DIM] = w_a;
    ws[j + 2 * OUT_DIM] = w_b;
    ws[j + 3 * OUT_DIM] = w_c;
    unsigned int* pk = (unsigned int*)(ws + 4 * OUT_DIM);
    pk[j] = (unsigned int)a_idx[j] | ((unsigned int)b_idx[j] << 16);
}

// Kernel 2: grid = BATCH/RROWS, TPB=1024, 128 KB dynamic LDS.
// Stage rows {4i..4i+3} interleaved (in-register transpose via 4 coalesced
// dword loads per k); per column: 1 pk + 4 weight loads (double-buffered) +
// 2 b128 gathers -> 4 outputs; NT f32x4 stores.
__global__ __launch_bounds__(TPB, 4) void gate_eval_kernel(
    const float* __restrict__ x,
    const float* __restrict__ ws,
    f32x4* __restrict__ out4) {
    extern __shared__ f32x4 rows4[];               // IN_DIM entries = 128 KB
    const int i0 = blockIdx.x * RROWS;

    const f32x4* wab4 = (const f32x4*)(ws);
    const f32x4* wa4  = (const f32x4*)(ws + OUT_DIM);
    const f32x4* wb4  = (const f32x4*)(ws + 2 * OUT_DIM);
    const f32x4* wc4  = (const f32x4*)(ws + 3 * OUT_DIM);
    const u32x4* pk4  = (const u32x4*)(ws + 4 * OUT_DIM);

    // Prefetch iter-0 table BEFORE staging (in flight during staging loads).
    u32x4 pkb[2];
    f32x4 wabb[2], wab_[2], wbb[2], wcb[2];
    {
        int j4 = threadIdx.x;
        pkb[0]  = pk4[j4];
        wabb[0] = wab4[j4];
        wab_[0] = wa4[j4];
        wbb[0]  = wb4[j4];
        wcb[0]  = wc4[j4];
    }

    // Stage: for each k, gather the 4 rows' values (4 coalesced dword loads)
    // and write one b128 (consecutive-lane b128 = conflict-free).
    const float* x0 = x + (size_t)i0 * IN_DIM;
#pragma unroll
    for (int t = 0; t < IN_DIM / TPB; ++t) {       // 8 iters
        int k = threadIdx.x + t * TPB;
        f32x4 p;
        p.x = x0[k];
        p.y = x0[k + IN_DIM];
        p.z = x0[k + 2 * IN_DIM];
        p.w = x0[k + 3 * IN_DIM];
        rows4[k] = p;
    }
    __syncthreads();

    f32x4* o0 = out4 + (size_t)i0 * (OUT_DIM / 4);
    f32x4* o1 = o0 + (OUT_DIM / 4);
    f32x4* o2 = o1 + (OUT_DIM / 4);
    f32x4* o3 = o2 + (OUT_DIM / 4);

#pragma unroll
    for (int k = 0; k < NITER; ++k) {              // 4, fully unrolled
        const int cur = k & 1, nxt = cur ^ 1;
        if (k + 1 < NITER) {                       // prefetch next table
            int j4n = threadIdx.x + (k + 1) * TPB;
            pkb[nxt]  = pk4[j4n];
            wabb[nxt] = wab4[j4n];
            wab_[nxt] = wa4[j4n];
            wbb[nxt]  = wb4[j4n];
            wcb[nxt]  = wc4[j4n];
        }
        int j4 = threadIdx.x + k * TPB;
        u32x4 pk = pkb[cur];
        f32x4 wab = wabb[cur], wa = wab_[cur], wb = wbb[cur], wc = wcb[cur];
        f32x4 r0, r1, r2, r3;
#pragma unroll
        for (int c = 0; c < 4; ++c) {
            f32x4 va = rows4[pk[c] & 0xFFFFu];     // {x0[ia],x1[ia],x2[ia],x3[ia]}
            f32x4 vb = rows4[pk[c] >> 16];
            r0[c] = fmaf(wab[c], va.x * vb.x,
                         fmaf(wa[c], va.x, fmaf(wb[c], vb.x, wc[c])));
            r1[c] = fmaf(wab[c], va.y * vb.y,
                         fmaf(wa[c], va.y, fmaf(wb[c], vb.y, wc[c])));
            r2[c] = fmaf(wab[c], va.z * vb.z,
                         fmaf(wa[c], va.z, fmaf(wb[c], vb.z, wc[c])));
            r3[c] = fmaf(wab[c], va.w * vb.w,
                         fmaf(wa[c], va.w, fmaf(wb[c], vb.w, wc[c])));
        }
        __builtin_nontemporal_store(r0, &o0[j4]);
        __builtin_nontemporal_store(r1, &o1[j4]);
        __builtin_nontemporal_store(r2, &o2[j4]);
        __builtin_nontemporal_store(r3, &o3[j4]);
    }
}

// Fallback if ws_size is too small: recompute softmax inline per column.
__global__ __launch_bounds__(256) void gate_eval_fused_kernel(
    const float* __restrict__ x,
    const float* __restrict__ logits,
    const int* __restrict__ a_idx,
    const int* __restrict__ b_idx,
    float* __restrict__ out) {
    __shared__ float row[IN_DIM];
    const int i = blockIdx.x;
    const f32x4* xr = (const f32x4*)(x + (size_t)i * IN_DIM);
    f32x4* rv = (f32x4*)row;
#pragma unroll
    for (int t = 0; t < IN_DIM / 4 / 256; ++t)
        rv[threadIdx.x + t * 256] = xr[threadIdx.x + t * 256];
    __syncthreads();
    float* o = out + (size_t)i * OUT_DIM;
    for (int k = 0; k < OUT_DIM / 256; ++k) {
        int j = threadIdx.x + k * 256;
        float w_ab, w_a, w_b, w_c;
        collapse_weights(logits + (size_t)j * NG, w_ab, w_a, w_b, w_c);
        float a = row[a_idx[j]], b = row[b_idx[j]];
        o[j] = fmaf(w_ab, a * b, fmaf(w_a, a, fmaf(w_b, b, w_c)));
    }
}

extern "C" void kernel_launch(void* const* d_in, const int* in_sizes, int n_in,
                              void* d_out, int out_size, void* d_ws, size_t ws_size,
                              hipStream_t stream) {
    const float* x      = (const float*)d_in[0];
    const float* logits = (const float*)d_in[1];
    const int*   a_idx  = (const int*)d_in[2];
    const int*   b_idx  = (const int*)d_in[3];
    float* out = (float*)d_out;

    const size_t ws_need = (size_t)(4 * OUT_DIM) * sizeof(float)
                         + (size_t)OUT_DIM * sizeof(unsigned int);  // 320 KB
    if (ws_size >= ws_need && d_ws != nullptr) {
        float* ws = (float*)d_ws;
        gate_weights_kernel<<<OUT_DIM / 256, 256, 0, stream>>>(
            logits, a_idx, b_idx, ws);
        gate_eval_kernel<<<BATCH / RROWS, TPB,
                           (size_t)IN_DIM * sizeof(f32x4), stream>>>(
            x, ws, (f32x4*)out);
    } else {
        gate_eval_fused_kernel<<<BATCH, 256, 0, stream>>>(
            x, logits, a_idx, b_idx, out);
    }
}

// Round 10
// 40.372 us; speedup vs baseline: 1.0944x; 1.0944x over previous
//
#include <hip/hip_runtime.h>
#include <hip/hip_bf16.h>

#define IN_DIM  8192
#define OUT_DIM 16384
#define BATCH   2048
#define NG      16
#define RROWS   4     // batch rows per block, packed as 4x bf16 (8 B) per index
#define TPB     512
#define NITER   (OUT_DIM / 4 / TPB)   // 8

typedef float        f32x4 __attribute__((ext_vector_type(4)));
typedef unsigned int u32x2 __attribute__((ext_vector_type(2)));
typedef unsigned int u32x4 __attribute__((ext_vector_type(4)));

// ---------------------------------------------------------------------------
// Gate mixture is linear in {a*b, a, b, 1}: out = w_ab*ab + w_a*a + w_b*b + w_c.
// ws layout (SoA): [w_ab | w_a | w_b | w_c] (4*OUT_DIM f32), then packed
// indices (OUT_DIM u32: a_idx | b_idx<<16).
// Eval: rows 4i..4i+3 packed as 4x bf16 per index (8 B) -> ONE ds_read_b64
// per operand serves 4 rows' outputs, LDS stays 64 KB (2 blocks/CU — round-9
// showed 1 block/CU serializes staging). Weights stay fp32; only the x
// operand is bf16-rounded (error budget ~0.006 < 0.0192 threshold).
// ---------------------------------------------------------------------------

__device__ __forceinline__ void collapse_weights(const float* __restrict__ l,
                                                 float& w_ab, float& w_a,
                                                 float& w_b, float& w_c) {
    float v[NG];
    float m = -1e30f;
#pragma unroll
    for (int k = 0; k < NG; ++k) { v[k] = l[k]; m = fmaxf(m, v[k]); }
    float s = 0.f;
#pragma unroll
    for (int k = 0; k < NG; ++k) { v[k] = __expf(v[k] - m); s += v[k]; }
    float inv = 1.0f / s;
#pragma unroll
    for (int k = 0; k < NG; ++k) v[k] *= inv;
    w_ab = v[1] - v[2] - v[4] - 2.f * v[6] - v[7] + v[8] + 2.f * v[9]
         + v[11] + v[13] - v[14];
    w_a  = v[2] + v[3] + v[6] + v[7] - v[8] - v[9] - v[12] - v[13];
    w_b  = v[4] + v[5] + v[6] + v[7] - v[8] - v[9] - v[10] - v[11];
    w_c  = v[8] + v[9] + v[10] + v[11] + v[12] + v[13] + v[14] + v[15];
}

// Kernel 1: per-column softmax -> SoA coefficients + packed u16 index pairs.
__global__ __launch_bounds__(256) void gate_weights_kernel(
    const float* __restrict__ logits,
    const int* __restrict__ a_idx, const int* __restrict__ b_idx,
    float* __restrict__ ws) {
    int j = blockIdx.x * blockDim.x + threadIdx.x;
    if (j >= OUT_DIM) return;
    float w_ab, w_a, w_b, w_c;
    collapse_weights(logits + (size_t)j * NG, w_ab, w_a, w_b, w_c);
    ws[j]               = w_ab;
    ws[j +     OUT_DIM] = w_a;
    ws[j + 2 * OUT_DIM] = w_b;
    ws[j + 3 * OUT_DIM] = w_c;
    unsigned int* pk = (unsigned int*)(ws + 4 * OUT_DIM);
    pk[j] = (unsigned int)a_idx[j] | ((unsigned int)b_idx[j] << 16);
}

__device__ __forceinline__ float bf16_hi_to_f(unsigned int u) {
    union { unsigned int i; float f; } c; c.i = u & 0xFFFF0000u; return c.f;
}
__device__ __forceinline__ float bf16_lo_to_f(unsigned int u) {
    union { unsigned int i; float f; } c; c.i = u << 16; return c.f;
}

// Kernel 2: grid = BATCH/RROWS, TPB=512, 64 KB LDS (2 blocks/CU).
// Stage rows {4i..4i+3} as packed bf16x4 per index; per column: 1 pk +
// 4 weight f32x4 loads (double-buffered) + 2 b64 gathers -> 4 outputs;
// NT f32x4 stores.
__global__ __launch_bounds__(TPB, 4) void gate_eval_kernel(
    const float* __restrict__ x,
    const float* __restrict__ ws,
    f32x4* __restrict__ out4) {
    __shared__ u32x2 rowsp[IN_DIM];                // 64 KB
    const int i0 = blockIdx.x * RROWS;

    const f32x4* wab4 = (const f32x4*)(ws);
    const f32x4* wa4  = (const f32x4*)(ws + OUT_DIM);
    const f32x4* wb4  = (const f32x4*)(ws + 2 * OUT_DIM);
    const f32x4* wc4  = (const f32x4*)(ws + 3 * OUT_DIM);
    const u32x4* pk4  = (const u32x4*)(ws + 4 * OUT_DIM);

    // Prefetch iter-0 table BEFORE staging (in flight during staging loads).
    u32x4 pkb[2];
    f32x4 wabb[2], wab_[2], wbb[2], wcb[2];
    {
        int j4 = threadIdx.x;
        pkb[0]  = pk4[j4];
        wabb[0] = wab4[j4];
        wab_[0] = wa4[j4];
        wbb[0]  = wb4[j4];
        wcb[0]  = wc4[j4];
    }

    // Stage: per index k, 4 coalesced dword loads (one per row), RN-convert
    // to bf16, pack to 8 B, single b64 write (consecutive-lane => free).
    const float* x0 = x + (size_t)i0 * IN_DIM;
#pragma unroll
    for (int t = 0; t < IN_DIM / TPB; ++t) {       // 16 iters
        int k = threadIdx.x + t * TPB;
        unsigned short b0 = __bfloat16_as_ushort(__float2bfloat16(x0[k]));
        unsigned short b1 = __bfloat16_as_ushort(__float2bfloat16(x0[k + IN_DIM]));
        unsigned short b2 = __bfloat16_as_ushort(__float2bfloat16(x0[k + 2 * IN_DIM]));
        unsigned short b3 = __bfloat16_as_ushort(__float2bfloat16(x0[k + 3 * IN_DIM]));
        u32x2 p;
        p.x = (unsigned int)b0 | ((unsigned int)b1 << 16);
        p.y = (unsigned int)b2 | ((unsigned int)b3 << 16);
        rowsp[k] = p;
    }
    __syncthreads();

    f32x4* o0 = out4 + (size_t)i0 * (OUT_DIM / 4);
    f32x4* o1 = o0 + (OUT_DIM / 4);
    f32x4* o2 = o1 + (OUT_DIM / 4);
    f32x4* o3 = o2 + (OUT_DIM / 4);

#pragma unroll
    for (int k = 0; k < NITER; ++k) {              // 8, fully unrolled
        const int cur = k & 1, nxt = cur ^ 1;
        if (k + 1 < NITER) {                       // prefetch next table
            int j4n = threadIdx.x + (k + 1) * TPB;
            pkb[nxt]  = pk4[j4n];
            wabb[nxt] = wab4[j4n];
            wab_[nxt] = wa4[j4n];
            wbb[nxt]  = wb4[j4n];
            wcb[nxt]  = wc4[j4n];
        }
        int j4 = threadIdx.x + k * TPB;
        u32x4 pk = pkb[cur];
        f32x4 wab = wabb[cur], wa = wab_[cur], wb = wbb[cur], wc = wcb[cur];
        f32x4 r0, r1, r2, r3;
#pragma unroll
        for (int c = 0; c < 4; ++c) {
            u32x2 va = rowsp[pk[c] & 0xFFFFu];
            u32x2 vb = rowsp[pk[c] >> 16];
            float a0 = bf16_lo_to_f(va.x), a1 = bf16_hi_to_f(va.x);
            float a2 = bf16_lo_to_f(va.y), a3 = bf16_hi_to_f(va.y);
            float b0 = bf16_lo_to_f(vb.x), b1 = bf16_hi_to_f(vb.x);
            float b2 = bf16_lo_to_f(vb.y), b3 = bf16_hi_to_f(vb.y);
            r0[c] = fmaf(wab[c], a0 * b0, fmaf(wa[c], a0, fmaf(wb[c], b0, wc[c])));
            r1[c] = fmaf(wab[c], a1 * b1, fmaf(wa[c], a1, fmaf(wb[c], b1, wc[c])));
            r2[c] = fmaf(wab[c], a2 * b2, fmaf(wa[c], a2, fmaf(wb[c], b2, wc[c])));
            r3[c] = fmaf(wab[c], a3 * b3, fmaf(wa[c], a3, fmaf(wb[c], b3, wc[c])));
        }
        __builtin_nontemporal_store(r0, &o0[j4]);
        __builtin_nontemporal_store(r1, &o1[j4]);
        __builtin_nontemporal_store(r2, &o2[j4]);
        __builtin_nontemporal_store(r3, &o3[j4]);
    }
}

// Fallback if ws_size is too small: recompute softmax inline per column.
__global__ __launch_bounds__(256) void gate_eval_fused_kernel(
    const float* __restrict__ x,
    const float* __restrict__ logits,
    const int* __restrict__ a_idx,
    const int* __restrict__ b_idx,
    float* __restrict__ out) {
    __shared__ float row[IN_DIM];
    const int i = blockIdx.x;
    const f32x4* xr = (const f32x4*)(x + (size_t)i * IN_DIM);
    f32x4* rv = (f32x4*)row;
#pragma unroll
    for (int t = 0; t < IN_DIM / 4 / 256; ++t)
        rv[threadIdx.x + t * 256] = xr[threadIdx.x + t * 256];
    __syncthreads();
    float* o = out + (size_t)i * OUT_DIM;
    for (int k = 0; k < OUT_DIM / 256; ++k) {
        int j = threadIdx.x + k * 256;
        float w_ab, w_a, w_b, w_c;
        collapse_weights(logits + (size_t)j * NG, w_ab, w_a, w_b, w_c);
        float a = row[a_idx[j]], b = row[b_idx[j]];
        o[j] = fmaf(w_ab, a * b, fmaf(w_a, a, fmaf(w_b, b, w_c)));
    }
}

extern "C" void kernel_launch(void* const* d_in, const int* in_sizes, int n_in,
                              void* d_out, int out_size, void* d_ws, size_t ws_size,
                              hipStream_t stream) {
    const float* x      = (const float*)d_in[0];
    const float* logits = (const float*)d_in[1];
    const int*   a_idx  = (const int*)d_in[2];
    const int*   b_idx  = (const int*)d_in[3];
    float* out = (float*)d_out;

    const size_t ws_need = (size_t)(4 * OUT_DIM) * sizeof(float)
                         + (size_t)OUT_DIM * sizeof(unsigned int);  // 320 KB
    if (ws_size >= ws_need && d_ws != nullptr) {
        float* ws = (float*)d_ws;
        gate_weights_kernel<<<OUT_DIM / 256, 256, 0, stream>>>(
            logits, a_idx, b_idx, ws);
        gate_eval_kernel<<<BATCH / RROWS, TPB, 0, stream>>>(
            x, ws, (f32x4*)out);
    } else {
        gate_eval_fused_kernel<<<BATCH, 256, 0, stream>>>(
            x, logits, a_idx, b_idx, out);
    }
}